// Round 1
// baseline (9.738 us; speedup 1.0000x reference)
//
#include <hip/hip_runtime.h>
#include <hip/hip_bf16.h>

// Problem constants (from reference):
//   CLASSES = 81, NUM_ROIS = 32
//   out_regr: (1, 32, 320) f32   d_in[0]
//   out_class:(1, 32, 81)  f32   d_in[1]
//   rois:     (1, 32, 4)   f32   d_in[2]
//   b:        (1,600,1000,3) f32 d_in[3]  -- shape only: H=600, W=1000
//   masks:    (80, 1, 32)  i32   d_in[4]
// Output: (80, 1, 32, 85) f32 = 217600 elements.
//   out[c][0][r][j] = j<81 ? out_class[r][j]*m : coords(r,c,j-81)*m
//   m = masks[c][0][r]

#define NCLS 81
#define NROIS 32
#define NC1 80          // CLASSES-1
#define ROWLEN 85       // 81 + 4
#define TOTAL (NC1 * NROIS * ROWLEN)   // 217600

__global__ __launch_bounds__(256) void bb_creation_kernel(
    const float* __restrict__ regr,     // (32, 320)
    const float* __restrict__ cls,      // (32, 81)
    const float* __restrict__ rois,     // (32, 4)
    const int*   __restrict__ masks,    // (80, 32)
    float* __restrict__ out)            // (80, 32, 85)
{
    int idx = blockIdx.x * blockDim.x + threadIdx.x;
    if (idx >= TOTAL) return;

    int c   = idx / (NROIS * ROWLEN);
    int rem = idx - c * (NROIS * ROWLEN);
    int r   = rem / ROWLEN;
    int j   = rem - r * ROWLEN;

    float m = (float)masks[c * NROIS + r];

    float val;
    if (j < NCLS) {
        val = cls[r * NCLS + j];
    } else {
        int k = j - NCLS;
        // t = regr[r, c*4 + k] / STD, STD = {8,8,4,4}
        const float* tr = regr + r * (4 * NC1) + c * 4;
        float t0 = tr[0] * 0.125f;
        float t1 = tr[1] * 0.125f;
        float t2 = tr[2] * 0.25f;
        float t3 = tr[3] * 0.25f;

        float x = rois[r * 4 + 0];
        float y = rois[r * 4 + 1];
        float w = rois[r * 4 + 2];
        float h = rois[r * 4 + 3];
        float cx = x + w * 0.5f;
        float cy = y + h * 0.5f;

        float cx1 = t0 * w + cx;
        float cy1 = t1 * h + cy;
        float w1  = __expf(t2) * w;   // fast exp; see note below if accuracy trips
        float h1  = __expf(t3) * h;
        // jnp.round = round half to even -> rintf (RTNE default)
        float gx = rintf(cx1 - w1 * 0.5f);
        float gy = rintf(cy1 - h1 * 0.5f);
        float gw = rintf(w1);
        float gh = rintf(h1);

        const float invW = 1.0f / 1000.0f;
        const float invH = 1.0f / 600.0f;
        if      (k == 0) val = gx * invW;
        else if (k == 1) val = gy * invH;
        else if (k == 2) val = (gx + gw) * invW;
        else             val = (gy + gh) * invH;
    }

    out[idx] = val * m;
}

extern "C" void kernel_launch(void* const* d_in, const int* in_sizes, int n_in,
                              void* d_out, int out_size, void* d_ws, size_t ws_size,
                              hipStream_t stream) {
    const float* regr  = (const float*)d_in[0];
    const float* cls   = (const float*)d_in[1];
    const float* rois  = (const float*)d_in[2];
    // d_in[3] (b) unused: only its shape (600x1000) matters, hardcoded.
    const int*   masks = (const int*)d_in[4];
    float* out = (float*)d_out;

    int threads = 256;
    int blocks = (TOTAL + threads - 1) / threads;   // 850
    bb_creation_kernel<<<blocks, threads, 0, stream>>>(regr, cls, rois, masks, out);
}

// Round 2
// 9.662 us; speedup vs baseline: 1.0078x; 1.0078x over previous
//
#include <hip/hip_runtime.h>
#include <hip/hip_bf16.h>

// Problem constants (from reference):
//   CLASSES = 81, NUM_ROIS = 32
//   out_regr: (1, 32, 320) f32   d_in[0]
//   out_class:(1, 32, 81)  f32   d_in[1]
//   rois:     (1, 32, 4)   f32   d_in[2]
//   b:        (1,600,1000,3) f32 d_in[3]  -- shape only: H=600, W=1000
//   masks:    (80, 1, 32)  i32   d_in[4]
// Output: (80, 1, 32, 85) f32 = 217600 elements (divisible by 4).
//   out[c][0][r][j] = (j<81 ? out_class[r][j] : coords(r,c,j-81)) * masks[c][0][r]

#define NCLS 81
#define NROIS 32
#define NC1 80          // CLASSES-1
#define ROWLEN 85       // 81 + 4
#define TOTAL (NC1 * NROIS * ROWLEN)   // 217600
#define TOTAL4 (TOTAL / 4)             // 54400

__device__ __forceinline__ float elem_val(
    int idx,
    const float* __restrict__ regr,
    const float* __restrict__ cls,
    const float* __restrict__ rois,
    const int*   __restrict__ masks)
{
    int c   = idx / (NROIS * ROWLEN);          // magic-mul
    int rem = idx - c * (NROIS * ROWLEN);
    int r   = rem / ROWLEN;                    // magic-mul
    int j   = rem - r * ROWLEN;

    float m = (float)masks[c * NROIS + r];

    float val;
    if (j < NCLS) {
        val = cls[r * NCLS + j];
    } else {
        int k = j - NCLS;
        const float* tr = regr + r * (4 * NC1) + c * 4;
        float t0 = tr[0] * 0.125f;
        float t1 = tr[1] * 0.125f;
        float t2 = tr[2] * 0.25f;
        float t3 = tr[3] * 0.25f;

        float x = rois[r * 4 + 0];
        float y = rois[r * 4 + 1];
        float w = rois[r * 4 + 2];
        float h = rois[r * 4 + 3];
        float cx = x + w * 0.5f;
        float cy = y + h * 0.5f;

        float cx1 = t0 * w + cx;
        float cy1 = t1 * h + cy;
        float w1  = __expf(t2) * w;
        float h1  = __expf(t3) * h;
        float gx = rintf(cx1 - w1 * 0.5f);   // jnp.round = RTNE
        float gy = rintf(cy1 - h1 * 0.5f);
        float gw = rintf(w1);
        float gh = rintf(h1);

        const float invW = 1.0f / 1000.0f;
        const float invH = 1.0f / 600.0f;
        if      (k == 0) val = gx * invW;
        else if (k == 1) val = gy * invH;
        else if (k == 2) val = (gx + gw) * invW;
        else             val = (gy + gh) * invH;
    }
    return val * m;
}

__global__ __launch_bounds__(256) void bb_creation_kernel_v4(
    const float* __restrict__ regr,
    const float* __restrict__ cls,
    const float* __restrict__ rois,
    const int*   __restrict__ masks,
    float4* __restrict__ out)
{
    int t = blockIdx.x * blockDim.x + threadIdx.x;
    if (t >= TOTAL4) return;

    int base = t * 4;
    float4 v;
    v.x = elem_val(base + 0, regr, cls, rois, masks);
    v.y = elem_val(base + 1, regr, cls, rois, masks);
    v.z = elem_val(base + 2, regr, cls, rois, masks);
    v.w = elem_val(base + 3, regr, cls, rois, masks);
    out[t] = v;
}

extern "C" void kernel_launch(void* const* d_in, const int* in_sizes, int n_in,
                              void* d_out, int out_size, void* d_ws, size_t ws_size,
                              hipStream_t stream) {
    const float* regr  = (const float*)d_in[0];
    const float* cls   = (const float*)d_in[1];
    const float* rois  = (const float*)d_in[2];
    // d_in[3] (b) unused: only its shape (600x1000) matters, hardcoded.
    const int*   masks = (const int*)d_in[4];
    float4* out = (float4*)d_out;

    int threads = 256;
    int blocks = (TOTAL4 + threads - 1) / threads;   // 213
    bb_creation_kernel_v4<<<blocks, threads, 0, stream>>>(regr, cls, rois, masks, out);
}